// Round 2
// baseline (1388.431 us; speedup 1.0000x reference)
//
#include <hip/hip_runtime.h>
#include <stdint.h>
#include <math.h>

#define T_SEQ 2048
#define NHEAD 16
#define HD 64
#define DMODEL 1024
#define CDIM 1088
#define MROWS 4096

typedef uint16_t u16;
typedef __bf16 b8v __attribute__((ext_vector_type(8)));
typedef float f4v __attribute__((ext_vector_type(4)));

__device__ __forceinline__ float b2f(u16 u) {
  union { uint32_t i; float f; } c; c.i = ((uint32_t)u) << 16; return c.f;
}
__device__ __forceinline__ u16 f2b(float f) {
  union { float f; uint32_t i; } c; c.f = f;
  uint32_t x = c.i;
  return (u16)((x + 0x7fffu + ((x >> 16) & 1u)) >> 16);
}
__device__ __forceinline__ float gelu_f(float x) {
  return 0.5f * x * (1.0f + erff(x * 0.70710678118654752f));
}

// ---------------- time MLP (f32 in, f32 out) ---------------------------------
__global__ void time_mlp_kernel(const float* __restrict__ t, const float* __restrict__ w1,
                                const float* __restrict__ b1, const float* __restrict__ w2,
                                const float* __restrict__ b2, float* __restrict__ temb) {
  __shared__ float h1[2][64];
  int tid = threadIdx.x;            // 128 threads
  int b = tid >> 6, i = tid & 63;
  float tv = t[b];
  h1[b][i] = gelu_f(tv * w1[i] + b1[i]);
  __syncthreads();
  float acc = b2[i];
  for (int k = 0; k < 64; ++k) acc += h1[b][k] * w2[k * 64 + i];
  temb[b * 64 + i] = acc;
}

// ---------------- transpose + cast: src f32[R][C] -> dst bf16[C][R] ----------
__global__ __launch_bounds__(256) void transpose_kernel(const float* __restrict__ src,
                                                        u16* __restrict__ dst,
                                                        int R, int C) {
  __shared__ u16 tile[32][33];
  int tx = threadIdx.x & 31, ty = threadIdx.x >> 5;   // ty 0..7
  int c0 = blockIdx.x * 32, r0 = blockIdx.y * 32;
#pragma unroll
  for (int i = 0; i < 4; ++i) {
    int r = ty + i * 8;
    tile[r][tx] = f2b(src[(size_t)(r0 + r) * C + c0 + tx]);
  }
  __syncthreads();
#pragma unroll
  for (int i = 0; i < 4; ++i) {
    int c = ty + i * 8;
    dst[(size_t)(c0 + c) * R + r0 + tx] = tile[tx][c];
  }
}

// ---------------- fused concat(zin, t_emb) + LayerNorm -> bf16 ---------------
// in_f32 != 0: read zf (f32); else read zb (bf16)
__global__ __launch_bounds__(256) void ln_concat_kernel(const float* __restrict__ zf,
                                                        const u16* __restrict__ zb,
                                                        const float* __restrict__ temb,
                                                        const float* __restrict__ w,
                                                        const float* __restrict__ bvec,
                                                        u16* __restrict__ xout,
                                                        int in_f32) {
  __shared__ float red[4];
  int row = blockIdx.x;
  int b = row / T_SEQ;
  int tid = threadIdx.x;
  float v[5];
  float sum = 0.f;
#pragma unroll
  for (int i = 0; i < 5; ++i) {
    int c = tid + i * 256;
    float val = 0.f;
    if (c < CDIM) {
      if (c < DMODEL)
        val = in_f32 ? zf[(size_t)row * DMODEL + c] : b2f(zb[(size_t)row * DMODEL + c]);
      else
        val = temb[b * 64 + (c - DMODEL)];
    }
    v[i] = val;
    sum += val;
  }
#pragma unroll
  for (int off = 32; off; off >>= 1) sum += __shfl_xor(sum, off, 64);
  int wv = tid >> 6, ln = tid & 63;
  if (ln == 0) red[wv] = sum;
  __syncthreads();
  float mean = (red[0] + red[1] + red[2] + red[3]) * (1.0f / CDIM);
  __syncthreads();
  float sq = 0.f;
#pragma unroll
  for (int i = 0; i < 5; ++i) {
    int c = tid + i * 256;
    if (c < CDIM) { float d = v[i] - mean; sq += d * d; }
  }
#pragma unroll
  for (int off = 32; off; off >>= 1) sq += __shfl_xor(sq, off, 64);
  if (ln == 0) red[wv] = sq;
  __syncthreads();
  float inv = rsqrtf((red[0] + red[1] + red[2] + red[3]) * (1.0f / CDIM) + 1e-5f);
#pragma unroll
  for (int i = 0; i < 5; ++i) {
    int c = tid + i * 256;
    if (c < CDIM)
      xout[(size_t)row * CDIM + c] = f2b((v[i] - mean) * inv * w[c] + bvec[c]);
  }
}

// ---------------- GEMM: C[M][N] = act(A[M][K] @ Bt[N][K]^T + bias) -----------
// A, Bt bf16; bias f32; output bf16 (out_f32=0) or f32 (out_f32=1).
// 128x128 tile, BK=32, 4 waves in 2x2, each wave 4x4 grid of 16x16x32 MFMA.
__global__ __launch_bounds__(256) void gemm_bt_kernel(const u16* __restrict__ A,
                                                      const u16* __restrict__ Bt,
                                                      const float* __restrict__ bias,
                                                      void* __restrict__ Cout,
                                                      int M, int N, int K,
                                                      int do_gelu, int out_f32) {
  __shared__ u16 As[128 * 40];   // stride 40 (80B, 16B-aligned) to pad banks
  __shared__ u16 Bs[128 * 40];
  const int tid = threadIdx.x;
  const int wave = tid >> 6, lane = tid & 63;
  const int wr = wave >> 1, wc = wave & 1;
  const int m0 = blockIdx.x * 128;
  const int n0 = blockIdx.y * 128;
  const int lrow = lane & 15, quad = lane >> 4;

  f4v acc[4][4] = {};

  for (int k0 = 0; k0 < K; k0 += 32) {
    __syncthreads();
#pragma unroll
    for (int i = 0; i < 2; ++i) {
      int idx = tid + i * 256;
      int row = idx >> 2, seg = idx & 3;
      uint4 av = *(const uint4*)(A + (size_t)(m0 + row) * K + k0 + seg * 8);
      *(uint4*)(&As[row * 40 + seg * 8]) = av;
      uint4 bv = *(const uint4*)(Bt + (size_t)(n0 + row) * K + k0 + seg * 8);
      *(uint4*)(&Bs[row * 40 + seg * 8]) = bv;
    }
    __syncthreads();
    b8v af[4], bfr[4];
#pragma unroll
    for (int mi = 0; mi < 4; ++mi)
      af[mi] = *(const b8v*)(&As[(wr * 64 + mi * 16 + lrow) * 40 + quad * 8]);
#pragma unroll
    for (int ni = 0; ni < 4; ++ni)
      bfr[ni] = *(const b8v*)(&Bs[(wc * 64 + ni * 16 + lrow) * 40 + quad * 8]);
#pragma unroll
    for (int mi = 0; mi < 4; ++mi)
#pragma unroll
      for (int ni = 0; ni < 4; ++ni)
        acc[mi][ni] = __builtin_amdgcn_mfma_f32_16x16x32_bf16(af[mi], bfr[ni], acc[mi][ni], 0, 0, 0);
  }

#pragma unroll
  for (int mi = 0; mi < 4; ++mi) {
#pragma unroll
    for (int ni = 0; ni < 4; ++ni) {
      int gcol = n0 + wc * 64 + ni * 16 + lrow;
      float bv = bias[gcol];
#pragma unroll
      for (int r = 0; r < 4; ++r) {
        int grow = m0 + wr * 64 + mi * 16 + quad * 4 + r;
        float v = acc[mi][ni][r] + bv;
        if (do_gelu) v = gelu_f(v);
        if (out_f32)
          ((float*)Cout)[(size_t)grow * N + gcol] = v;
        else
          ((u16*)Cout)[(size_t)grow * N + gcol] = f2b(v);
      }
    }
  }
}

// ---------------- causal attention (flash, non-MFMA baseline) ----------------
// grid = (B*H, T/4); block = 256 (4 waves, 1 q-row per wave)
__global__ __launch_bounds__(256) void attn_kernel(const u16* __restrict__ qkv,
                                                   u16* __restrict__ y) {
  __shared__ float Kb[64][68];
  __shared__ float Vb[64][68];
  __shared__ float Qs[4][68];
  __shared__ float Ps[4][68];
  const int bh = blockIdx.x;
  const int b = bh >> 4, h = bh & 15;
  const int qt = blockIdx.y;
  const int tid = threadIdx.x, wv = tid >> 6, lane = tid & 63;
  const int q = qt * 4 + wv;
  const int qmax = qt * 4 + 3;

  Qs[wv][lane] = b2f(qkv[(size_t)(b * T_SEQ + q) * 3072 + h * 64 + lane]) * 0.125f;
  float m = -__builtin_inff(), lsum = 0.f, o = 0.f;

  const int r = tid >> 2, d0 = (tid & 3) * 16;
  const int nch = (qmax >> 6) + 1;
  for (int ct = 0; ct < nch; ++ct) {
    __syncthreads();   // previous PV done; Qs visible
    {
      size_t base = (size_t)(b * T_SEQ + ct * 64 + r) * 3072 + h * 64 + d0;
#pragma unroll
      for (int i = 0; i < 2; ++i) {
        uint4 kv = *(const uint4*)(qkv + base + 1024 + i * 8);
        uint4 vv = *(const uint4*)(qkv + base + 2048 + i * 8);
        float kt[8], vt[8];
        kt[0] = b2f((u16)(kv.x & 0xffff)); kt[1] = b2f((u16)(kv.x >> 16));
        kt[2] = b2f((u16)(kv.y & 0xffff)); kt[3] = b2f((u16)(kv.y >> 16));
        kt[4] = b2f((u16)(kv.z & 0xffff)); kt[5] = b2f((u16)(kv.z >> 16));
        kt[6] = b2f((u16)(kv.w & 0xffff)); kt[7] = b2f((u16)(kv.w >> 16));
        vt[0] = b2f((u16)(vv.x & 0xffff)); vt[1] = b2f((u16)(vv.x >> 16));
        vt[2] = b2f((u16)(vv.y & 0xffff)); vt[3] = b2f((u16)(vv.y >> 16));
        vt[4] = b2f((u16)(vv.z & 0xffff)); vt[5] = b2f((u16)(vv.z >> 16));
        vt[6] = b2f((u16)(vv.w & 0xffff)); vt[7] = b2f((u16)(vv.w >> 16));
#pragma unroll
        for (int j = 0; j < 8; ++j) {
          Kb[r][d0 + i * 8 + j] = kt[j];
          Vb[r][d0 + i * 8 + j] = vt[j];
        }
      }
    }
    __syncthreads();
    // scores: lane = key within chunk
    float s = 0.f;
    const float4* qrow = (const float4*)(&Qs[wv][0]);
    const float4* krow = (const float4*)(&Kb[lane][0]);
#pragma unroll
    for (int d4 = 0; d4 < 16; ++d4) {
      float4 a = qrow[d4], k4 = krow[d4];
      s += a.x * k4.x + a.y * k4.y + a.z * k4.z + a.w * k4.w;
    }
    int key = ct * 64 + lane;
    if (key > q) s = -__builtin_inff();
    float cm = s;
#pragma unroll
    for (int off = 32; off; off >>= 1) cm = fmaxf(cm, __shfl_xor(cm, off, 64));
    float mnew = fmaxf(m, cm);
    float alpha = expf(m - mnew);        // m=-inf only on chunk 0 -> alpha=0
    float p = expf(s - mnew);            // s=-inf (masked) -> p=0
    float psum = p;
#pragma unroll
    for (int off = 32; off; off >>= 1) psum += __shfl_xor(psum, off, 64);
    lsum = lsum * alpha + psum;
    m = mnew;
    o *= alpha;
    Ps[wv][lane] = p;
    __syncthreads();
    // PV: lane = d
#pragma unroll 8
    for (int k = 0; k < 64; ++k) o += Ps[wv][k] * Vb[k][lane];
  }
  y[(size_t)(b * T_SEQ + q) * DMODEL + h * 64 + lane] = f2b(o / lsum);
}

// ----------------------------------------------------------------------------
extern "C" void kernel_launch(void* const* d_in, const int* in_sizes, int n_in,
                              void* d_out, int out_size, void* d_ws, size_t ws_size,
                              hipStream_t stream) {
  const float* z      = (const float*)d_in[0];
  const float* t      = (const float*)d_in[1];
  const float* w_t1   = (const float*)d_in[2];
  const float* b_t1   = (const float*)d_in[3];
  const float* w_t2   = (const float*)d_in[4];
  const float* b_t2   = (const float*)d_in[5];
  const float* ln_a_w = (const float*)d_in[6];
  const float* ln_a_b = (const float*)d_in[7];
  const float* w_attn = (const float*)d_in[8];
  const float* b_attn = (const float*)d_in[9];
  const float* w_proj = (const float*)d_in[10];
  const float* b_proj = (const float*)d_in[11];
  const float* ln_m_w = (const float*)d_in[12];
  const float* ln_m_b = (const float*)d_in[13];
  const float* w_fc   = (const float*)d_in[14];
  const float* b_fc   = (const float*)d_in[15];
  const float* w_fc2  = (const float*)d_in[16];
  const float* b_fc2  = (const float*)d_in[17];

  char* ws = (char*)d_ws;
  float* temb  = (float*)ws;                               // 512 B (pad 1 KiB)
  u16* wT_attn = (u16*)(ws + 1024);                        // [3072][1088]
  u16* wT_proj = wT_attn + (size_t)3072 * 1088;            // [1024][1024]
  u16* wT_fc   = wT_proj + (size_t)1024 * 1024;            // [4096][1088]
  u16* wT_fc2  = wT_fc   + (size_t)4096 * 1088;            // [1024][4096]
  u16* xbuf    = wT_fc2  + (size_t)1024 * 4096;            // x / m  [4096][1088]
  u16* big     = xbuf    + (size_t)4096 * 1088;            // qkv then g [4096][4096]
  u16* ybuf    = big     + (size_t)4096 * 4096;            // [4096][1024]
  u16* hbuf    = ybuf    + (size_t)4096 * 1024;            // [4096][1024]

  time_mlp_kernel<<<dim3(1), dim3(128), 0, stream>>>(t, w_t1, b_t1, w_t2, b_t2, temb);

  transpose_kernel<<<dim3(3072 / 32, 1088 / 32), dim3(256), 0, stream>>>(w_attn, wT_attn, 1088, 3072);
  transpose_kernel<<<dim3(1024 / 32, 1024 / 32), dim3(256), 0, stream>>>(w_proj, wT_proj, 1024, 1024);
  transpose_kernel<<<dim3(4096 / 32, 1088 / 32), dim3(256), 0, stream>>>(w_fc, wT_fc, 1088, 4096);
  transpose_kernel<<<dim3(1024 / 32, 4096 / 32), dim3(256), 0, stream>>>(w_fc2, wT_fc2, 4096, 1024);

  ln_concat_kernel<<<dim3(MROWS), dim3(256), 0, stream>>>(z, (const u16*)nullptr, temb,
                                                          ln_a_w, ln_a_b, xbuf, 1);

  gemm_bt_kernel<<<dim3(MROWS / 128, 3072 / 128), dim3(256), 0, stream>>>(
      xbuf, wT_attn, b_attn, big, MROWS, 3072, 1088, 0, 0);

  attn_kernel<<<dim3(32, T_SEQ / 4), dim3(256), 0, stream>>>(big, ybuf);

  gemm_bt_kernel<<<dim3(MROWS / 128, 1024 / 128), dim3(256), 0, stream>>>(
      ybuf, wT_proj, b_proj, hbuf, MROWS, 1024, 1024, 0, 0);

  ln_concat_kernel<<<dim3(MROWS), dim3(256), 0, stream>>>((const float*)nullptr, hbuf, temb,
                                                          ln_m_w, ln_m_b, xbuf, 0);

  gemm_bt_kernel<<<dim3(MROWS / 128, 4096 / 128), dim3(256), 0, stream>>>(
      xbuf, wT_fc, b_fc, big, MROWS, 4096, 1088, 1, 0);

  gemm_bt_kernel<<<dim3(MROWS / 128, 1024 / 128), dim3(256), 0, stream>>>(
      big, wT_fc2, b_fc2, d_out, MROWS, 1024, 4096, 0, 1);
}

// Round 3
// 487.104 us; speedup vs baseline: 2.8504x; 2.8504x over previous
//
#include <hip/hip_runtime.h>
#include <stdint.h>
#include <math.h>

#define T_SEQ 2048
#define NHEAD 16
#define HD 64
#define DMODEL 1024
#define CDIM 1088
#define MROWS 4096

typedef uint16_t u16;
typedef __bf16 b8v __attribute__((ext_vector_type(8)));
typedef float f4v __attribute__((ext_vector_type(4)));

__device__ __forceinline__ float b2f(u16 u) {
  union { uint32_t i; float f; } c; c.i = ((uint32_t)u) << 16; return c.f;
}
__device__ __forceinline__ u16 f2b(float f) {
  union { float f; uint32_t i; } c; c.f = f;
  uint32_t x = c.i;
  return (u16)((x + 0x7fffu + ((x >> 16) & 1u)) >> 16);
}
__device__ __forceinline__ float gelu_f(float x) {
  return 0.5f * x * (1.0f + erff(x * 0.70710678118654752f));
}

// ---------------- time MLP (f32 in, f32 out) ---------------------------------
__global__ void time_mlp_kernel(const float* __restrict__ t, const float* __restrict__ w1,
                                const float* __restrict__ b1, const float* __restrict__ w2,
                                const float* __restrict__ b2, float* __restrict__ temb) {
  __shared__ float h1[2][64];
  int tid = threadIdx.x;            // 128 threads
  int b = tid >> 6, i = tid & 63;
  float tv = t[b];
  h1[b][i] = gelu_f(tv * w1[i] + b1[i]);
  __syncthreads();
  float acc = b2[i];
  for (int k = 0; k < 64; ++k) acc += h1[b][k] * w2[k * 64 + i];
  temb[b * 64 + i] = acc;
}

// ---------------- transpose + cast: src f32[R][C] -> dst bf16[C][R] ----------
__global__ __launch_bounds__(256) void transpose_kernel(const float* __restrict__ src,
                                                        u16* __restrict__ dst,
                                                        int R, int C) {
  __shared__ u16 tile[32][33];
  int tx = threadIdx.x & 31, ty = threadIdx.x >> 5;   // ty 0..7
  int c0 = blockIdx.x * 32, r0 = blockIdx.y * 32;
#pragma unroll
  for (int i = 0; i < 4; ++i) {
    int r = ty + i * 8;
    tile[r][tx] = f2b(src[(size_t)(r0 + r) * C + c0 + tx]);
  }
  __syncthreads();
#pragma unroll
  for (int i = 0; i < 4; ++i) {
    int c = ty + i * 8;
    dst[(size_t)(c0 + c) * R + r0 + tx] = tile[tx][c];
  }
}

// ---------------- fused concat(zin, t_emb) + LayerNorm -> bf16 ---------------
__global__ __launch_bounds__(256) void ln_concat_kernel(const float* __restrict__ zf,
                                                        const u16* __restrict__ zb,
                                                        const float* __restrict__ temb,
                                                        const float* __restrict__ w,
                                                        const float* __restrict__ bvec,
                                                        u16* __restrict__ xout,
                                                        int in_f32) {
  __shared__ float red[4];
  int row = blockIdx.x;
  int b = row / T_SEQ;
  int tid = threadIdx.x;
  float v[5];
  float sum = 0.f;
#pragma unroll
  for (int i = 0; i < 5; ++i) {
    int c = tid + i * 256;
    float val = 0.f;
    if (c < CDIM) {
      if (c < DMODEL)
        val = in_f32 ? zf[(size_t)row * DMODEL + c] : b2f(zb[(size_t)row * DMODEL + c]);
      else
        val = temb[b * 64 + (c - DMODEL)];
    }
    v[i] = val;
    sum += val;
  }
#pragma unroll
  for (int off = 32; off; off >>= 1) sum += __shfl_xor(sum, off, 64);
  int wv = tid >> 6, ln = tid & 63;
  if (ln == 0) red[wv] = sum;
  __syncthreads();
  float mean = (red[0] + red[1] + red[2] + red[3]) * (1.0f / CDIM);
  __syncthreads();
  float sq = 0.f;
#pragma unroll
  for (int i = 0; i < 5; ++i) {
    int c = tid + i * 256;
    if (c < CDIM) { float d = v[i] - mean; sq += d * d; }
  }
#pragma unroll
  for (int off = 32; off; off >>= 1) sq += __shfl_xor(sq, off, 64);
  if (ln == 0) red[wv] = sq;
  __syncthreads();
  float inv = rsqrtf((red[0] + red[1] + red[2] + red[3]) * (1.0f / CDIM) + 1e-5f);
#pragma unroll
  for (int i = 0; i < 5; ++i) {
    int c = tid + i * 256;
    if (c < CDIM)
      xout[(size_t)row * CDIM + c] = f2b((v[i] - mean) * inv * w[c] + bvec[c]);
  }
}

// ---------------- GEMM: C[M][N] = act(A[M][K] @ Bt[N][K]^T + bias) -----------
__global__ __launch_bounds__(256) void gemm_bt_kernel(const u16* __restrict__ A,
                                                      const u16* __restrict__ Bt,
                                                      const float* __restrict__ bias,
                                                      void* __restrict__ Cout,
                                                      int M, int N, int K,
                                                      int do_gelu, int out_f32) {
  __shared__ u16 As[128 * 40];
  __shared__ u16 Bs[128 * 40];
  const int tid = threadIdx.x;
  const int wave = tid >> 6, lane = tid & 63;
  const int wr = wave >> 1, wc = wave & 1;
  const int m0 = blockIdx.x * 128;
  const int n0 = blockIdx.y * 128;
  const int lrow = lane & 15, quad = lane >> 4;

  f4v acc[4][4] = {};

  for (int k0 = 0; k0 < K; k0 += 32) {
    __syncthreads();
#pragma unroll
    for (int i = 0; i < 2; ++i) {
      int idx = tid + i * 256;
      int row = idx >> 2, seg = idx & 3;
      uint4 av = *(const uint4*)(A + (size_t)(m0 + row) * K + k0 + seg * 8);
      *(uint4*)(&As[row * 40 + seg * 8]) = av;
      uint4 bv = *(const uint4*)(Bt + (size_t)(n0 + row) * K + k0 + seg * 8);
      *(uint4*)(&Bs[row * 40 + seg * 8]) = bv;
    }
    __syncthreads();
    b8v af[4], bfr[4];
#pragma unroll
    for (int mi = 0; mi < 4; ++mi)
      af[mi] = *(const b8v*)(&As[(wr * 64 + mi * 16 + lrow) * 40 + quad * 8]);
#pragma unroll
    for (int ni = 0; ni < 4; ++ni)
      bfr[ni] = *(const b8v*)(&Bs[(wc * 64 + ni * 16 + lrow) * 40 + quad * 8]);
#pragma unroll
    for (int mi = 0; mi < 4; ++mi)
#pragma unroll
      for (int ni = 0; ni < 4; ++ni)
        acc[mi][ni] = __builtin_amdgcn_mfma_f32_16x16x32_bf16(af[mi], bfr[ni], acc[mi][ni], 0, 0, 0);
  }

#pragma unroll
  for (int mi = 0; mi < 4; ++mi) {
#pragma unroll
    for (int ni = 0; ni < 4; ++ni) {
      int gcol = n0 + wc * 64 + ni * 16 + lrow;
      float bv = bias[gcol];
#pragma unroll
      for (int r = 0; r < 4; ++r) {
        int grow = m0 + wr * 64 + mi * 16 + quad * 4 + r;
        float v = acc[mi][ni][r] + bv;
        if (do_gelu) v = gelu_f(v);
        if (out_f32)
          ((float*)Cout)[(size_t)grow * N + gcol] = v;
        else
          ((u16*)Cout)[(size_t)grow * N + gcol] = f2b(v);
      }
    }
  }
}

// ---------------- MFMA flash attention ---------------------------------------
// grid = (B*H=32, 16); block = 256. Block handles 128 q-rows of one (b,h).
// Wave w owns q-rows [w*32, w*32+32). KV chunks of 64 keys.
__global__ __launch_bounds__(256) void attn_mfma_kernel(const u16* __restrict__ qkv,
                                                        u16* __restrict__ y) {
  __shared__ u16 Ks[64 * 72];           // K row-major  [key][d], stride 72
  __shared__ u16 Vts[64 * 72];          // V transposed [d][key^swz], stride 72
  __shared__ u16 Ps[128 * 72];          // per-wave 32 rows of P, stride 72
  const int bh = blockIdx.x;
  const int b = bh >> 4, h = bh & 15;
  const int yb = blockIdx.y;
  const int qt = (yb < 8) ? (yb * 2) : (31 - yb * 2);   // pair (2y, 15-2y): const load/CU
  const int tid = threadIdx.x, w = tid >> 6, lane = tid & 63;
  const int lrow = lane & 15, quad = lane >> 4;
  const int q0 = qt * 128;

  // preload Q fragments (A-operand layout: row=lrow, k = dc*32 + quad*8..+7)
  b8v qf[2][2];
#pragma unroll
  for (int s = 0; s < 2; ++s)
#pragma unroll
    for (int dc = 0; dc < 2; ++dc) {
      int row = q0 + w * 32 + s * 16 + lrow;
      qf[s][dc] = *(const b8v*)(qkv + (size_t)(b * T_SEQ + row) * 3072 + h * 64 + dc * 32 + quad * 8);
    }

  f4v oacc[2][4] = {};
  float mst[2][4], lst[2][4];
#pragma unroll
  for (int s = 0; s < 2; ++s)
#pragma unroll
    for (int r = 0; r < 4; ++r) { mst[s][r] = -__builtin_inff(); lst[s][r] = 0.f; }

  const int nch = 2 * qt + 2;
  for (int ct = 0; ct < nch; ++ct) {
    __syncthreads();   // LDS reuse guard
    // ---- stage K: thread -> row tid>>2, 16 cols
    {
      int r = tid >> 2, sg = tid & 3;
      const u16* src = qkv + (size_t)(b * T_SEQ + ct * 64 + r) * 3072 + h * 64 + 1024 + sg * 16;
      uint4 k1 = *(const uint4*)(src);
      uint4 k2 = *(const uint4*)(src + 8);
      *(uint4*)(&Ks[r * 72 + sg * 16]) = k1;
      *(uint4*)(&Ks[r * 72 + sg * 16 + 8]) = k2;
    }
    // ---- stage V transposed (pair-pack) with XOR swizzle on key index
    {
      int pr = tid >> 3, dsg = tid & 7;   // key pair 2pr, d-segment dsg*8..+7
      const u16* v0 = qkv + (size_t)(b * T_SEQ + ct * 64 + 2 * pr) * 3072 + h * 64 + 2048 + dsg * 8;
      uint4 a = *(const uint4*)(v0);
      uint4 bb = *(const uint4*)(v0 + 3072);
      uint32_t aw[4] = {a.x, a.y, a.z, a.w};
      uint32_t bw[4] = {bb.x, bb.y, bb.z, bb.w};
#pragma unroll
      for (int j = 0; j < 8; ++j) {
        int d = dsg * 8 + j;
        u16 ae = (u16)(aw[j >> 1] >> ((j & 1) * 16));
        u16 be = (u16)(bw[j >> 1] >> ((j & 1) * 16));
        int keyp = (2 * pr) ^ (((d >> 3) & 7) * 8);
        *(uint32_t*)(&Vts[d * 72 + keyp]) = (uint32_t)ae | ((uint32_t)be << 16);
      }
    }
    __syncthreads();

    // ---- S = Q K^T  (per wave: 2 qstrips x 4 kstrips)
    f4v sacc[2][4] = {};
    b8v kf[4][2];
#pragma unroll
    for (int ks = 0; ks < 4; ++ks)
#pragma unroll
      for (int dc = 0; dc < 2; ++dc)
        kf[ks][dc] = *(const b8v*)(&Ks[(ks * 16 + lrow) * 72 + dc * 32 + quad * 8]);
#pragma unroll
    for (int s = 0; s < 2; ++s)
#pragma unroll
      for (int ks = 0; ks < 4; ++ks)
#pragma unroll
        for (int dc = 0; dc < 2; ++dc)
          sacc[s][ks] = __builtin_amdgcn_mfma_f32_16x16x32_bf16(qf[s][dc], kf[ks][dc], sacc[s][ks], 0, 0, 0);

    // ---- scale + causal mask
    bool diag = (ct >= 2 * qt);
#pragma unroll
    for (int s = 0; s < 2; ++s)
#pragma unroll
      for (int ks = 0; ks < 4; ++ks) {
        int col = ct * 64 + ks * 16 + lrow;
#pragma unroll
        for (int r = 0; r < 4; ++r) {
          float v = sacc[s][ks][r] * 0.125f;
          int row = q0 + w * 32 + s * 16 + quad * 4 + r;
          if (diag && col > row) v = -__builtin_inff();
          sacc[s][ks][r] = v;
        }
      }

    // ---- online softmax (row state per (s, r); cols spread over 16 lanes x 4 ks)
#pragma unroll
    for (int s = 0; s < 2; ++s) {
#pragma unroll
      for (int r = 0; r < 4; ++r) {
        float rmax = fmaxf(fmaxf(sacc[s][0][r], sacc[s][1][r]), fmaxf(sacc[s][2][r], sacc[s][3][r]));
#pragma unroll
        for (int off = 1; off < 16; off <<= 1) rmax = fmaxf(rmax, __shfl_xor(rmax, off, 64));
        float mn = fmaxf(mst[s][r], rmax);
        float al = __expf(mst[s][r] - mn);
        mst[s][r] = mn;
        float psum = 0.f;
#pragma unroll
        for (int ks = 0; ks < 4; ++ks) {
          float p = __expf(sacc[s][ks][r] - mn);
          sacc[s][ks][r] = p;
          psum += p;
        }
#pragma unroll
        for (int off = 1; off < 16; off <<= 1) psum += __shfl_xor(psum, off, 64);
        lst[s][r] = lst[s][r] * al + psum;
#pragma unroll
        for (int ds = 0; ds < 4; ++ds) oacc[s][ds][r] *= al;
      }
    }

    // ---- P -> LDS (C/D layout -> row-major), then A-frags
#pragma unroll
    for (int s = 0; s < 2; ++s)
#pragma unroll
      for (int ks = 0; ks < 4; ++ks)
#pragma unroll
        for (int r = 0; r < 4; ++r)
          Ps[(w * 32 + s * 16 + quad * 4 + r) * 72 + ks * 16 + lrow] = f2b(sacc[s][ks][r]);

    b8v pf[2][2], vf[4][2];
#pragma unroll
    for (int s = 0; s < 2; ++s)
#pragma unroll
      for (int kc = 0; kc < 2; ++kc)
        pf[s][kc] = *(const b8v*)(&Ps[(w * 32 + s * 16 + lrow) * 72 + kc * 32 + quad * 8]);
#pragma unroll
    for (int ds = 0; ds < 4; ++ds)
#pragma unroll
      for (int kc = 0; kc < 2; ++kc) {
        int d = ds * 16 + lrow;
        int off = (kc * 32 + quad * 8) ^ (((d >> 3) & 7) * 8);
        vf[ds][kc] = *(const b8v*)(&Vts[d * 72 + off]);
      }
#pragma unroll
    for (int s = 0; s < 2; ++s)
#pragma unroll
      for (int ds = 0; ds < 4; ++ds)
#pragma unroll
        for (int kc = 0; kc < 2; ++kc)
          oacc[s][ds] = __builtin_amdgcn_mfma_f32_16x16x32_bf16(pf[s][kc], vf[ds][kc], oacc[s][ds], 0, 0, 0);
  }

  // ---- epilogue: O / l
#pragma unroll
  for (int s = 0; s < 2; ++s)
#pragma unroll
    for (int ds = 0; ds < 4; ++ds)
#pragma unroll
      for (int r = 0; r < 4; ++r) {
        int row = q0 + w * 32 + s * 16 + quad * 4 + r;
        y[(size_t)(b * T_SEQ + row) * DMODEL + h * 64 + ds * 16 + lrow] =
            f2b(oacc[s][ds][r] / lst[s][r]);
      }
}

// ----------------------------------------------------------------------------
extern "C" void kernel_launch(void* const* d_in, const int* in_sizes, int n_in,
                              void* d_out, int out_size, void* d_ws, size_t ws_size,
                              hipStream_t stream) {
  const float* z      = (const float*)d_in[0];
  const float* t      = (const float*)d_in[1];
  const float* w_t1   = (const float*)d_in[2];
  const float* b_t1   = (const float*)d_in[3];
  const float* w_t2   = (const float*)d_in[4];
  const float* b_t2   = (const float*)d_in[5];
  const float* ln_a_w = (const float*)d_in[6];
  const float* ln_a_b = (const float*)d_in[7];
  const float* w_attn = (const float*)d_in[8];
  const float* b_attn = (const float*)d_in[9];
  const float* w_proj = (const float*)d_in[10];
  const float* b_proj = (const float*)d_in[11];
  const float* ln_m_w = (const float*)d_in[12];
  const float* ln_m_b = (const float*)d_in[13];
  const float* w_fc   = (const float*)d_in[14];
  const float* b_fc   = (const float*)d_in[15];
  const float* w_fc2  = (const float*)d_in[16];
  const float* b_fc2  = (const float*)d_in[17];

  char* ws = (char*)d_ws;
  float* temb  = (float*)ws;
  u16* wT_attn = (u16*)(ws + 1024);
  u16* wT_proj = wT_attn + (size_t)3072 * 1088;
  u16* wT_fc   = wT_proj + (size_t)1024 * 1024;
  u16* wT_fc2  = wT_fc   + (size_t)4096 * 1088;
  u16* xbuf    = wT_fc2  + (size_t)1024 * 4096;
  u16* big     = xbuf    + (size_t)4096 * 1088;
  u16* ybuf    = big     + (size_t)4096 * 4096;
  u16* hbuf    = ybuf    + (size_t)4096 * 1024;

  time_mlp_kernel<<<dim3(1), dim3(128), 0, stream>>>(t, w_t1, b_t1, w_t2, b_t2, temb);

  transpose_kernel<<<dim3(3072 / 32, 1088 / 32), dim3(256), 0, stream>>>(w_attn, wT_attn, 1088, 3072);
  transpose_kernel<<<dim3(1024 / 32, 1024 / 32), dim3(256), 0, stream>>>(w_proj, wT_proj, 1024, 1024);
  transpose_kernel<<<dim3(4096 / 32, 1088 / 32), dim3(256), 0, stream>>>(w_fc, wT_fc, 1088, 4096);
  transpose_kernel<<<dim3(1024 / 32, 4096 / 32), dim3(256), 0, stream>>>(w_fc2, wT_fc2, 4096, 1024);

  ln_concat_kernel<<<dim3(MROWS), dim3(256), 0, stream>>>(z, (const u16*)nullptr, temb,
                                                          ln_a_w, ln_a_b, xbuf, 1);

  gemm_bt_kernel<<<dim3(MROWS / 128, 3072 / 128), dim3(256), 0, stream>>>(
      xbuf, wT_attn, b_attn, big, MROWS, 3072, 1088, 0, 0);

  attn_mfma_kernel<<<dim3(32, 16), dim3(256), 0, stream>>>(big, ybuf);

  gemm_bt_kernel<<<dim3(MROWS / 128, 1024 / 128), dim3(256), 0, stream>>>(
      ybuf, wT_proj, b_proj, hbuf, MROWS, 1024, 1024, 0, 0);

  ln_concat_kernel<<<dim3(MROWS), dim3(256), 0, stream>>>((const float*)nullptr, hbuf, temb,
                                                          ln_m_w, ln_m_b, xbuf, 0);

  gemm_bt_kernel<<<dim3(MROWS / 128, 4096 / 128), dim3(256), 0, stream>>>(
      xbuf, wT_fc, b_fc, big, MROWS, 4096, 1088, 1, 0);

  gemm_bt_kernel<<<dim3(MROWS / 128, 1024 / 128), dim3(256), 0, stream>>>(
      big, wT_fc2, b_fc2, d_out, MROWS, 1024, 4096, 0, 1);
}

// Round 4
// 485.015 us; speedup vs baseline: 2.8627x; 1.0043x over previous
//
#include <hip/hip_runtime.h>
#include <stdint.h>
#include <math.h>

#define T_SEQ 2048
#define NHEAD 16
#define HD 64
#define DMODEL 1024
#define CDIM 1088
#define MROWS 4096

typedef uint16_t u16;
typedef __bf16 b8v __attribute__((ext_vector_type(8)));
typedef float f4v __attribute__((ext_vector_type(4)));

typedef __attribute__((address_space(3))) void lds_void;
typedef const __attribute__((address_space(1))) void glb_void;

__device__ __forceinline__ float b2f(u16 u) {
  union { uint32_t i; float f; } c; c.i = ((uint32_t)u) << 16; return c.f;
}
__device__ __forceinline__ u16 f2b(float f) {
  union { float f; uint32_t i; } c; c.f = f;
  uint32_t x = c.i;
  return (u16)((x + 0x7fffu + ((x >> 16) & 1u)) >> 16);
}
__device__ __forceinline__ float gelu_f(float x) {
  return 0.5f * x * (1.0f + erff(x * 0.70710678118654752f));
}

// ---------------- time MLP (f32 in, f32 out) ---------------------------------
__global__ void time_mlp_kernel(const float* __restrict__ t, const float* __restrict__ w1,
                                const float* __restrict__ b1, const float* __restrict__ w2,
                                const float* __restrict__ b2, float* __restrict__ temb) {
  __shared__ float h1[2][64];
  int tid = threadIdx.x;            // 128 threads
  int b = tid >> 6, i = tid & 63;
  float tv = t[b];
  h1[b][i] = gelu_f(tv * w1[i] + b1[i]);
  __syncthreads();
  float acc = b2[i];
  for (int k = 0; k < 64; ++k) acc += h1[b][k] * w2[k * 64 + i];
  temb[b * 64 + i] = acc;
}

// ---------------- transpose + cast: src f32[R][C] -> dst bf16[C][R] ----------
__global__ __launch_bounds__(256) void transpose_kernel(const float* __restrict__ src,
                                                        u16* __restrict__ dst,
                                                        int R, int C) {
  __shared__ u16 tile[32][33];
  int tx = threadIdx.x & 31, ty = threadIdx.x >> 5;   // ty 0..7
  int c0 = blockIdx.x * 32, r0 = blockIdx.y * 32;
#pragma unroll
  for (int i = 0; i < 4; ++i) {
    int r = ty + i * 8;
    tile[r][tx] = f2b(src[(size_t)(r0 + r) * C + c0 + tx]);
  }
  __syncthreads();
#pragma unroll
  for (int i = 0; i < 4; ++i) {
    int c = ty + i * 8;
    dst[(size_t)(c0 + c) * R + r0 + tx] = tile[tx][c];
  }
}

// ---------------- fused concat(zin, t_emb) + LayerNorm -> bf16 ---------------
__global__ __launch_bounds__(256) void ln_concat_kernel(const float* __restrict__ zf,
                                                        const u16* __restrict__ zb,
                                                        const float* __restrict__ temb,
                                                        const float* __restrict__ w,
                                                        const float* __restrict__ bvec,
                                                        u16* __restrict__ xout,
                                                        int in_f32) {
  __shared__ float red[4];
  int row = blockIdx.x;
  int b = row / T_SEQ;
  int tid = threadIdx.x;
  float v[5];
  float sum = 0.f;
#pragma unroll
  for (int i = 0; i < 5; ++i) {
    int c = tid + i * 256;
    float val = 0.f;
    if (c < CDIM) {
      if (c < DMODEL)
        val = in_f32 ? zf[(size_t)row * DMODEL + c] : b2f(zb[(size_t)row * DMODEL + c]);
      else
        val = temb[b * 64 + (c - DMODEL)];
    }
    v[i] = val;
    sum += val;
  }
#pragma unroll
  for (int off = 32; off; off >>= 1) sum += __shfl_xor(sum, off, 64);
  int wv = tid >> 6, ln = tid & 63;
  if (ln == 0) red[wv] = sum;
  __syncthreads();
  float mean = (red[0] + red[1] + red[2] + red[3]) * (1.0f / CDIM);
  __syncthreads();
  float sq = 0.f;
#pragma unroll
  for (int i = 0; i < 5; ++i) {
    int c = tid + i * 256;
    if (c < CDIM) { float d = v[i] - mean; sq += d * d; }
  }
#pragma unroll
  for (int off = 32; off; off >>= 1) sq += __shfl_xor(sq, off, 64);
  if (ln == 0) red[wv] = sq;
  __syncthreads();
  float inv = rsqrtf((red[0] + red[1] + red[2] + red[3]) * (1.0f / CDIM) + 1e-5f);
#pragma unroll
  for (int i = 0; i < 5; ++i) {
    int c = tid + i * 256;
    if (c < CDIM)
      xout[(size_t)row * CDIM + c] = f2b((v[i] - mean) * inv * w[c] + bvec[c]);
  }
}

// ---------------- GEMM: C[M][N] = act(A[M][K] @ Bt[N][K]^T + bias) -----------
// m97 structure: 128x128 tile, BK=32, global_load_lds width=16 staging,
// unpadded LDS stride 32, 4 waves in 2x2, each wave 4x4 of 16x16x32 MFMA.
__global__ __launch_bounds__(256) void gemm_bt_kernel(const u16* __restrict__ A,
                                                      const u16* __restrict__ Bt,
                                                      const float* __restrict__ bias,
                                                      void* __restrict__ Cout,
                                                      int M, int N, int K,
                                                      int do_gelu, int out_f32) {
  __shared__ u16 As[128 * 32];
  __shared__ u16 Bs[128 * 32];
  const int tid = threadIdx.x;
  const int wave = tid >> 6, lane = tid & 63;
  const int wr = wave >> 1, wc = wave & 1;
  const int m0 = blockIdx.x * 128;
  const int n0 = blockIdx.y * 128;
  const int lrow = lane & 15, quad = lane >> 4;
  const int srow = lane >> 2, sseg = lane & 3;   // staging: lane -> row/4, seg

  f4v acc[4][4] = {};

  for (int k0 = 0; k0 < K; k0 += 32) {
    __syncthreads();
    // each wave stages 32 rows of A and 32 rows of B (2 x 1024B each)
#pragma unroll
    for (int i = 0; i < 2; ++i) {
      int rbase = wave * 32 + i * 16;
      const u16* ga = A + (size_t)(m0 + rbase + srow) * K + k0 + sseg * 8;
      __builtin_amdgcn_global_load_lds((glb_void*)ga, (lds_void*)&As[rbase * 32], 16, 0, 0);
      const u16* gb = Bt + (size_t)(n0 + rbase + srow) * K + k0 + sseg * 8;
      __builtin_amdgcn_global_load_lds((glb_void*)gb, (lds_void*)&Bs[rbase * 32], 16, 0, 0);
    }
    __syncthreads();
    b8v af[4], bfr[4];
#pragma unroll
    for (int mi = 0; mi < 4; ++mi)
      af[mi] = *(const b8v*)(&As[(wr * 64 + mi * 16 + lrow) * 32 + quad * 8]);
#pragma unroll
    for (int ni = 0; ni < 4; ++ni)
      bfr[ni] = *(const b8v*)(&Bs[(wc * 64 + ni * 16 + lrow) * 32 + quad * 8]);
#pragma unroll
    for (int mi = 0; mi < 4; ++mi)
#pragma unroll
      for (int ni = 0; ni < 4; ++ni)
        acc[mi][ni] = __builtin_amdgcn_mfma_f32_16x16x32_bf16(af[mi], bfr[ni], acc[mi][ni], 0, 0, 0);
  }

#pragma unroll
  for (int mi = 0; mi < 4; ++mi) {
#pragma unroll
    for (int ni = 0; ni < 4; ++ni) {
      int gcol = n0 + wc * 64 + ni * 16 + lrow;
      float bv = bias[gcol];
#pragma unroll
      for (int r = 0; r < 4; ++r) {
        int grow = m0 + wr * 64 + mi * 16 + quad * 4 + r;
        float v = acc[mi][ni][r] + bv;
        if (do_gelu) v = gelu_f(v);
        if (out_f32)
          ((float*)Cout)[(size_t)grow * N + gcol] = v;
        else
          ((u16*)Cout)[(size_t)grow * N + gcol] = f2b(v);
      }
    }
  }
}

// ---------------- MFMA flash attention ---------------------------------------
// grid = (B*H=32, 16); block = 256. Block handles 128 q-rows of one (b,h).
__global__ __launch_bounds__(256) void attn_mfma_kernel(const u16* __restrict__ qkv,
                                                        u16* __restrict__ y) {
  __shared__ u16 Ks[64 * 72];           // K row-major  [key][d], stride 72
  __shared__ u16 Vts[64 * 72];          // V transposed [d][key^swz], stride 72
  __shared__ u16 Ps[128 * 72];          // per-wave 32 rows of P, stride 72
  const int bh = blockIdx.x;
  const int b = bh >> 4, h = bh & 15;
  const int yb = blockIdx.y;
  const int qt = (yb < 8) ? (yb * 2) : (31 - yb * 2);
  const int tid = threadIdx.x, w = tid >> 6, lane = tid & 63;
  const int lrow = lane & 15, quad = lane >> 4;
  const int q0 = qt * 128;

  b8v qf[2][2];
#pragma unroll
  for (int s = 0; s < 2; ++s)
#pragma unroll
    for (int dc = 0; dc < 2; ++dc) {
      int row = q0 + w * 32 + s * 16 + lrow;
      qf[s][dc] = *(const b8v*)(qkv + (size_t)(b * T_SEQ + row) * 3072 + h * 64 + dc * 32 + quad * 8);
    }

  f4v oacc[2][4] = {};
  float mst[2][4], lst[2][4];
#pragma unroll
  for (int s = 0; s < 2; ++s)
#pragma unroll
    for (int r = 0; r < 4; ++r) { mst[s][r] = -__builtin_inff(); lst[s][r] = 0.f; }

  const int nch = 2 * qt + 2;
  for (int ct = 0; ct < nch; ++ct) {
    __syncthreads();
    {
      int r = tid >> 2, sg = tid & 3;
      const u16* src = qkv + (size_t)(b * T_SEQ + ct * 64 + r) * 3072 + h * 64 + 1024 + sg * 16;
      uint4 k1 = *(const uint4*)(src);
      uint4 k2 = *(const uint4*)(src + 8);
      *(uint4*)(&Ks[r * 72 + sg * 16]) = k1;
      *(uint4*)(&Ks[r * 72 + sg * 16 + 8]) = k2;
    }
    {
      int pr = tid >> 3, dsg = tid & 7;
      const u16* v0 = qkv + (size_t)(b * T_SEQ + ct * 64 + 2 * pr) * 3072 + h * 64 + 2048 + dsg * 8;
      uint4 a = *(const uint4*)(v0);
      uint4 bb = *(const uint4*)(v0 + 3072);
      uint32_t aw[4] = {a.x, a.y, a.z, a.w};
      uint32_t bw[4] = {bb.x, bb.y, bb.z, bb.w};
#pragma unroll
      for (int j = 0; j < 8; ++j) {
        int d = dsg * 8 + j;
        u16 ae = (u16)(aw[j >> 1] >> ((j & 1) * 16));
        u16 be = (u16)(bw[j >> 1] >> ((j & 1) * 16));
        int keyp = (2 * pr) ^ (((d >> 3) & 7) * 8);
        *(uint32_t*)(&Vts[d * 72 + keyp]) = (uint32_t)ae | ((uint32_t)be << 16);
      }
    }
    __syncthreads();

    f4v sacc[2][4] = {};
    b8v kf[4][2];
#pragma unroll
    for (int ks = 0; ks < 4; ++ks)
#pragma unroll
      for (int dc = 0; dc < 2; ++dc)
        kf[ks][dc] = *(const b8v*)(&Ks[(ks * 16 + lrow) * 72 + dc * 32 + quad * 8]);
#pragma unroll
    for (int s = 0; s < 2; ++s)
#pragma unroll
      for (int ks = 0; ks < 4; ++ks)
#pragma unroll
        for (int dc = 0; dc < 2; ++dc)
          sacc[s][ks] = __builtin_amdgcn_mfma_f32_16x16x32_bf16(qf[s][dc], kf[ks][dc], sacc[s][ks], 0, 0, 0);

    bool diag = (ct >= 2 * qt);
#pragma unroll
    for (int s = 0; s < 2; ++s)
#pragma unroll
      for (int ks = 0; ks < 4; ++ks) {
        int col = ct * 64 + ks * 16 + lrow;
#pragma unroll
        for (int r = 0; r < 4; ++r) {
          float v = sacc[s][ks][r] * 0.125f;
          int row = q0 + w * 32 + s * 16 + quad * 4 + r;
          if (diag && col > row) v = -__builtin_inff();
          sacc[s][ks][r] = v;
        }
      }

#pragma unroll
    for (int s = 0; s < 2; ++s) {
#pragma unroll
      for (int r = 0; r < 4; ++r) {
        float rmax = fmaxf(fmaxf(sacc[s][0][r], sacc[s][1][r]), fmaxf(sacc[s][2][r], sacc[s][3][r]));
#pragma unroll
        for (int off = 1; off < 16; off <<= 1) rmax = fmaxf(rmax, __shfl_xor(rmax, off, 64));
        float mn = fmaxf(mst[s][r], rmax);
        float al = __expf(mst[s][r] - mn);
        mst[s][r] = mn;
        float psum = 0.f;
#pragma unroll
        for (int ks = 0; ks < 4; ++ks) {
          float p = __expf(sacc[s][ks][r] - mn);
          sacc[s][ks][r] = p;
          psum += p;
        }
#pragma unroll
        for (int off = 1; off < 16; off <<= 1) psum += __shfl_xor(psum, off, 64);
        lst[s][r] = lst[s][r] * al + psum;
#pragma unroll
        for (int ds = 0; ds < 4; ++ds) oacc[s][ds][r] *= al;
      }
    }

#pragma unroll
    for (int s = 0; s < 2; ++s)
#pragma unroll
      for (int ks = 0; ks < 4; ++ks)
#pragma unroll
        for (int r = 0; r < 4; ++r)
          Ps[(w * 32 + s * 16 + quad * 4 + r) * 72 + ks * 16 + lrow] = f2b(sacc[s][ks][r]);

    b8v pf[2][2], vf[4][2];
#pragma unroll
    for (int s = 0; s < 2; ++s)
#pragma unroll
      for (int kc = 0; kc < 2; ++kc)
        pf[s][kc] = *(const b8v*)(&Ps[(w * 32 + s * 16 + lrow) * 72 + kc * 32 + quad * 8]);
#pragma unroll
    for (int ds = 0; ds < 4; ++ds)
#pragma unroll
      for (int kc = 0; kc < 2; ++kc) {
        int d = ds * 16 + lrow;
        int off = (kc * 32 + quad * 8) ^ (((d >> 3) & 7) * 8);
        vf[ds][kc] = *(const b8v*)(&Vts[d * 72 + off]);
      }
#pragma unroll
    for (int s = 0; s < 2; ++s)
#pragma unroll
      for (int ds = 0; ds < 4; ++ds)
#pragma unroll
        for (int kc = 0; kc < 2; ++kc)
          oacc[s][ds] = __builtin_amdgcn_mfma_f32_16x16x32_bf16(pf[s][kc], vf[ds][kc], oacc[s][ds], 0, 0, 0);
  }

#pragma unroll
  for (int s = 0; s < 2; ++s)
#pragma unroll
    for (int ds = 0; ds < 4; ++ds)
#pragma unroll
      for (int r = 0; r < 4; ++r) {
        int row = q0 + w * 32 + s * 16 + quad * 4 + r;
        y[(size_t)(b * T_SEQ + row) * DMODEL + h * 64 + ds * 16 + lrow] =
            f2b(oacc[s][ds][r] / lst[s][r]);
      }
}

// ----------------------------------------------------------------------------
extern "C" void kernel_launch(void* const* d_in, const int* in_sizes, int n_in,
                              void* d_out, int out_size, void* d_ws, size_t ws_size,
                              hipStream_t stream) {
  const float* z      = (const float*)d_in[0];
  const float* t      = (const float*)d_in[1];
  const float* w_t1   = (const float*)d_in[2];
  const float* b_t1   = (const float*)d_in[3];
  const float* w_t2   = (const float*)d_in[4];
  const float* b_t2   = (const float*)d_in[5];
  const float* ln_a_w = (const float*)d_in[6];
  const float* ln_a_b = (const float*)d_in[7];
  const float* w_attn = (const float*)d_in[8];
  const float* b_attn = (const float*)d_in[9];
  const float* w_proj = (const float*)d_in[10];
  const float* b_proj = (const float*)d_in[11];
  const float* ln_m_w = (const float*)d_in[12];
  const float* ln_m_b = (const float*)d_in[13];
  const float* w_fc   = (const float*)d_in[14];
  const float* b_fc   = (const float*)d_in[15];
  const float* w_fc2  = (const float*)d_in[16];
  const float* b_fc2  = (const float*)d_in[17];

  char* ws = (char*)d_ws;
  float* temb  = (float*)ws;
  u16* wT_attn = (u16*)(ws + 1024);
  u16* wT_proj = wT_attn + (size_t)3072 * 1088;
  u16* wT_fc   = wT_proj + (size_t)1024 * 1024;
  u16* wT_fc2  = wT_fc   + (size_t)4096 * 1088;
  u16* xbuf    = wT_fc2  + (size_t)1024 * 4096;
  u16* big     = xbuf    + (size_t)4096 * 1088;
  u16* ybuf    = big     + (size_t)4096 * 4096;
  u16* hbuf    = ybuf    + (size_t)4096 * 1024;

  time_mlp_kernel<<<dim3(1), dim3(128), 0, stream>>>(t, w_t1, b_t1, w_t2, b_t2, temb);

  transpose_kernel<<<dim3(3072 / 32, 1088 / 32), dim3(256), 0, stream>>>(w_attn, wT_attn, 1088, 3072);
  transpose_kernel<<<dim3(1024 / 32, 1024 / 32), dim3(256), 0, stream>>>(w_proj, wT_proj, 1024, 1024);
  transpose_kernel<<<dim3(4096 / 32, 1088 / 32), dim3(256), 0, stream>>>(w_fc, wT_fc, 1088, 4096);
  transpose_kernel<<<dim3(1024 / 32, 4096 / 32), dim3(256), 0, stream>>>(w_fc2, wT_fc2, 4096, 1024);

  ln_concat_kernel<<<dim3(MROWS), dim3(256), 0, stream>>>(z, (const u16*)nullptr, temb,
                                                          ln_a_w, ln_a_b, xbuf, 1);

  gemm_bt_kernel<<<dim3(MROWS / 128, 3072 / 128), dim3(256), 0, stream>>>(
      xbuf, wT_attn, b_attn, big, MROWS, 3072, 1088, 0, 0);

  attn_mfma_kernel<<<dim3(32, 16), dim3(256), 0, stream>>>(big, ybuf);

  gemm_bt_kernel<<<dim3(MROWS / 128, 1024 / 128), dim3(256), 0, stream>>>(
      ybuf, wT_proj, b_proj, hbuf, MROWS, 1024, 1024, 0, 0);

  ln_concat_kernel<<<dim3(MROWS), dim3(256), 0, stream>>>((const float*)nullptr, hbuf, temb,
                                                          ln_m_w, ln_m_b, xbuf, 0);

  gemm_bt_kernel<<<dim3(MROWS / 128, 4096 / 128), dim3(256), 0, stream>>>(
      xbuf, wT_fc, b_fc, big, MROWS, 4096, 1088, 1, 0);

  gemm_bt_kernel<<<dim3(MROWS / 128, 1024 / 128), dim3(256), 0, stream>>>(
      big, wT_fc2, b_fc2, d_out, MROWS, 1024, 4096, 0, 1);
}